// Round 12
// baseline (164.146 us; speedup 1.0000x reference)
//
#include <hip/hip_runtime.h>
#include <hip/hip_bf16.h>

// B=2, H=16, S=2048, D=64, DMODEL=1024
// Round 12: attn restructured to ZERO-LDS / ZERO-BARRIER. convert_all now
// emits K and V as MFMA-fragment STREAMS (Kf[t][ks][lane][8], and
// Vf[t][s4][half][lane][8] with the PV kv-permutation baked in), so attn's
// loads are linear 1KB-coalesced global reads straight into fragments.
// Each wave owns 32 q-rows x all kv: no kh split, no __syncthreads, L via
// ones-MFMA (regs free at 2 waves/SIMD). r9/r11 plateaued at 54-56us from
// barrier convoying + the 31us DS bill; both are deleted here.

typedef float  f32x16 __attribute__((ext_vector_type(16)));
typedef float  f32x4v __attribute__((ext_vector_type(4)));
typedef __bf16 bf16x8 __attribute__((ext_vector_type(8)));
typedef __bf16 bf16x4 __attribute__((ext_vector_type(4)));
typedef __bf16 bf16x2 __attribute__((ext_vector_type(2)));

static constexpr int Bn = 2, Hn = 16, Sn = 2048, Dn = 64, DM = 1024;
static constexpr size_t QKV_ELEMS = (size_t)Bn * Hn * Sn * Dn;   // 4,194,304
static constexpr int HD = Sn * Dn;                                // 131072 els/head

#define QSCALE 0.18033688011112042f   // 0.125 * log2(e)

#if __has_builtin(__builtin_amdgcn_cvt_pk_bf16_f32)
static __device__ __forceinline__ unsigned pack2(float a, float b) {
  bf16x2 t = __builtin_amdgcn_cvt_pk_bf16_f32(a, b);
  union { bf16x2 v; unsigned u; } c; c.v = t; return c.u;
}
#else
static __device__ __forceinline__ unsigned pack2(float a, float b) {
  union { __bf16 h; unsigned short s; } ua, ub;
  ua.h = (__bf16)a; ub.h = (__bf16)b;
  return (unsigned)ua.s | ((unsigned)ub.s << 16);
}
#endif

static __device__ __forceinline__ void unzip8(const unsigned* wds, bf16x8* r0, bf16x8* r1) {
  union { unsigned u[4]; bf16x8 v; } a, b;
#pragma unroll
  for (int i = 0; i < 4; ++i) {
    unsigned lo = wds[2 * i], hi = wds[2 * i + 1];
    a.u[i] = (lo & 0xffffu) | (hi << 16);
    b.u[i] = (lo >> 16) | (hi & 0xffff0000u);
  }
  *r0 = a.v; *r1 = b.v;
}

// ------------------------------------------------- fused converts (1 kernel)
// [0,256):    K (b,h,kv,d) fp32 -> Kf fragment stream
//             Kf[head][t][ks][lane=ln+32g][j] = K[t*32+ln][ks*16+g*8+j]
// [256,1280): V (b,h,kv,d) fp32 -> Vf fragment stream (transpose via LDS)
//             Vf[head][t][s4][half][lane=(d&31)+32g][j]
//               = V^T[32*half+(d&31)][t*32+s4*16+g*4+8*(j>>2)+(j&3)]
// [1280,1536): W (k,n) fp32 -> Wt (n,k) bf16
__global__ __launch_bounds__(256) void convert_all(
    const float* __restrict__ k,
    const float* __restrict__ v, const float* __restrict__ w,
    __bf16* __restrict__ kf, __bf16* __restrict__ vf, __bf16* __restrict__ wt) {
  __shared__ __bf16 T[64][74];
  const int bid = blockIdx.x, t = threadIdx.x;

  if (bid < 256) {                       // ---- K fragment stream
    const int R = bid * 256 + t;         // row among B*H*S = 65536
    const int bh = R >> 11, r = R & 2047;
    const int tt = r >> 5, ln = r & 31;
    const float* src = k + (size_t)R * Dn;
    __bf16* dst = kf + (size_t)bh * HD;
#pragma unroll
    for (int c = 0; c < 8; ++c) {        // chunk c: ks=c>>1, g=c&1
      f32x4v f0 = *(const f32x4v*)(src + c * 8);
      f32x4v f1 = *(const f32x4v*)(src + c * 8 + 4);
      bf16x8 o;
#pragma unroll
      for (int j = 0; j < 4; ++j) { o[j] = (__bf16)f0[j]; o[4 + j] = (__bf16)f1[j]; }
      const int ks = c >> 1, g = c & 1;
      *(bf16x8*)(dst + ((size_t)(tt * 4 + ks) * 64 + ln + 32 * g) * 8) = o;
    }
    return;
  }

  // ---- V / W: 64x64 fp32 tile -> bf16 LDS (stride 74) -> transposed emit
  const int r = t >> 2, c0 = (t & 3) * 16;
  const float* s0;
  if (bid < 1280) {
    const int idx = bid - 256;
    const int kv0 = (idx & 31) * 64, bh = idx >> 5;
    s0 = v + ((size_t)bh * Sn + kv0 + r) * Dn + c0;
    union { bf16x8 v8; unsigned u[4]; } o0, o1;
#pragma unroll
    for (int i = 0; i < 2; ++i) {
      f32x4v f = *(const f32x4v*)(s0 + i * 4);
#pragma unroll
      for (int j = 0; j < 4; ++j) o0.v8[i * 4 + j] = (__bf16)f[j];
    }
#pragma unroll
    for (int i = 0; i < 2; ++i) {
      f32x4v f = *(const f32x4v*)(s0 + 8 + i * 4);
#pragma unroll
      for (int j = 0; j < 4; ++j) o1.v8[i * 4 + j] = (__bf16)f[j];
    }
#pragma unroll
    for (int j = 0; j < 4; ++j) {
      *(unsigned*)&T[r][c0 + 2 * j]     = o0.u[j];
      *(unsigned*)&T[r][c0 + 8 + 2 * j] = o1.u[j];
    }
    __syncthreads();
    const int rp = t >> 3, k0 = (t & 7) * 8;
    unsigned wds[8];
#pragma unroll
    for (int i = 0; i < 8; ++i) wds[i] = *(const unsigned*)&T[k0 + i][2 * rp];
    bf16x8 r0, r1; unzip8(wds, &r0, &r1);
    // fragment emit: rows d0,d0+1 x kv [kvL..kvL+7]
    const int kvL = kv0 + k0;
    const int tt = (kvL >> 5) & 63, s4 = (kvL >> 4) & 1, jo = ((kvL >> 3) & 1) * 4;
    const int d0 = 2 * rp, half = d0 >> 5, lnd = d0 & 31;
    __bf16* vb = vf + (size_t)(idx >> 5) * HD +
                 (size_t)((tt * 2 + s4) * 2 + half) * 512;
    union { bf16x8 v8; bf16x4 h[2]; } a0, a1; a0.v8 = r0; a1.v8 = r1;
    *(bf16x4*)(vb + (lnd)*8 + jo)      = a0.h[0];   // kv lo-4 -> g=0 lane
    *(bf16x4*)(vb + (lnd + 32) * 8 + jo) = a0.h[1]; // kv hi-4 -> g=1 lane
    *(bf16x4*)(vb + (lnd + 1) * 8 + jo)  = a1.h[0];
    *(bf16x4*)(vb + (lnd + 33) * 8 + jo) = a1.h[1];
    return;
  }
  {
    const int idx = bid - 1280;
    const int nt = (idx & 15) * 64, kt = (idx >> 4) * 64;
    s0 = w + (size_t)(kt + r) * DM + nt + c0;
    union { bf16x8 v8; unsigned u[4]; } o0, o1;
#pragma unroll
    for (int i = 0; i < 2; ++i) {
      f32x4v f = *(const f32x4v*)(s0 + i * 4);
#pragma unroll
      for (int j = 0; j < 4; ++j) o0.v8[i * 4 + j] = (__bf16)f[j];
    }
#pragma unroll
    for (int i = 0; i < 2; ++i) {
      f32x4v f = *(const f32x4v*)(s0 + 8 + i * 4);
#pragma unroll
      for (int j = 0; j < 4; ++j) o1.v8[i * 4 + j] = (__bf16)f[j];
    }
#pragma unroll
    for (int j = 0; j < 4; ++j) {
      *(unsigned*)&T[r][c0 + 2 * j]     = o0.u[j];
      *(unsigned*)&T[r][c0 + 8 + 2 * j] = o1.u[j];
    }
    __syncthreads();
    const int rp = t >> 3, k0 = (t & 7) * 8;
    unsigned wds[8];
#pragma unroll
    for (int i = 0; i < 8; ++i) wds[i] = *(const unsigned*)&T[k0 + i][2 * rp];
    bf16x8 r0, r1; unzip8(wds, &r0, &r1);
    __bf16* d0 = wt + (size_t)(nt + 2 * rp) * DM + kt + k0;
    *(bf16x8*)d0 = r0;
    *(bf16x8*)(d0 + DM) = r1;
  }
}

// ---------------------------------------------------------------- attention
// grid (S/128, H, B) = 512 blocks x 4 waves; each wave = 32 q rows x all kv.
// NO LDS in the loop, NO barriers anywhere: K/V fragments stream from global
// (linear 1KB-coalesced loads), register double-buffered. L via ones-MFMA.
// Per-wave epilogue transpose through a private LDS region (same-wave DS is
// in-order; no __syncthreads needed).
__global__ __launch_bounds__(256, 2) void attn(
    const float* __restrict__ Qf, const __bf16* __restrict__ Kf,
    const __bf16* __restrict__ Vf, __bf16* __restrict__ Cc) {
  const int tid = threadIdx.x;
  const int wave = tid >> 6, lane = tid & 63;
  const int ln = lane & 31, g = lane >> 5;
  const int qb = blockIdx.x, h = blockIdx.y, bz = blockIdx.z;
  const int bh = bz * Hn + h;

  __shared__ __bf16 T[4][32][72];          // per-wave epilogue regions

  const float* Qp = Qf + (size_t)bh * HD + (size_t)(qb * 128 + wave * 32) * Dn;
  const __bf16* kbase = Kf + (size_t)bh * HD + (size_t)lane * 8;
  const __bf16* vbase = Vf + (size_t)bh * HD + (size_t)lane * 8;

  // Q A/B-fragments: fp32 load + scale + cvt (prologue only)
  bf16x8 qf[4];
#pragma unroll
  for (int ks = 0; ks < 4; ++ks) {
    const float* qp = Qp + (size_t)ln * Dn + ks * 16 + g * 8;
    f32x4v f0 = *(const f32x4v*)qp;
    f32x4v f1 = *(const f32x4v*)(qp + 4);
#pragma unroll
    for (int j = 0; j < 4; ++j) {
      qf[ks][j]     = (__bf16)(f0[j] * QSCALE);
      qf[ks][4 + j] = (__bf16)(f1[j] * QSCALE);
    }
  }
  bf16x8 ones;
#pragma unroll
  for (int i = 0; i < 8; ++i) ones[i] = (__bf16)1.0f;

  f32x16 O0 = {}, O1 = {}, Ls = {};
  constexpr int NT = Sn / 32;              // 64 iterations of 32 kv

  bf16x8 kfr[2][4], vfr[2][4];
#pragma unroll
  for (int ks = 0; ks < 4; ++ks) kfr[0][ks] = *(const bf16x8*)(kbase + (size_t)ks * 512);
#pragma unroll
  for (int u = 0; u < 4; ++u)    vfr[0][u]  = *(const bf16x8*)(vbase + (size_t)u * 512);

#pragma unroll 2
  for (int kt = 0; kt < NT; ++kt) {
    const int cur = kt & 1, nxt = cur ^ 1;
    if (kt + 1 < NT) {                     // prefetch next 32-kv tile
      const __bf16* kp = kbase + (size_t)(kt + 1) * 2048;
      const __bf16* vp = vbase + (size_t)(kt + 1) * 2048;
#pragma unroll
      for (int ks = 0; ks < 4; ++ks) kfr[nxt][ks] = *(const bf16x8*)(kp + (size_t)ks * 512);
#pragma unroll
      for (int u = 0; u < 4; ++u)    vfr[nxt][u]  = *(const bf16x8*)(vp + (size_t)u * 512);
    }

    // S^T 32kv x 32q; p = exp2(s) (log2e folded into Q)
    f32x16 s = {};
#pragma unroll
    for (int ks = 0; ks < 4; ++ks)
      s = __builtin_amdgcn_mfma_f32_32x32x16_bf16(kfr[cur][ks], qf[ks], s, 0, 0, 0);
    unsigned w[8];
#pragma unroll
    for (int tt = 0; tt < 8; ++tt)
      w[tt] = pack2(__builtin_amdgcn_exp2f(s[2 * tt]),
                    __builtin_amdgcn_exp2f(s[2 * tt + 1]));

    // PV (+L): B-frag words verbatim (kv-permutation baked into Vf)
#pragma unroll
    for (int s4 = 0; s4 < 2; ++s4) {
      union { unsigned u[4]; bf16x8 v; } pu;
      pu.u[0] = w[s4 * 4 + 0];
      pu.u[1] = w[s4 * 4 + 1];
      pu.u[2] = w[s4 * 4 + 2];
      pu.u[3] = w[s4 * 4 + 3];
      O0 = __builtin_amdgcn_mfma_f32_32x32x16_bf16(vfr[cur][s4 * 2 + 0], pu.v, O0, 0, 0, 0);
      O1 = __builtin_amdgcn_mfma_f32_32x32x16_bf16(vfr[cur][s4 * 2 + 1], pu.v, O1, 0, 0, 0);
      Ls = __builtin_amdgcn_mfma_f32_32x32x16_bf16(ones, pu.v, Ls, 0, 0, 0);
    }
  }

  // ---- per-wave epilogue: normalize, LDS transpose, coalesced store ----
  const float inv = 1.0f / Ls[0];          // all Ls regs equal L(q=ln)
  __bf16* Tw = &T[wave][0][0];
#pragma unroll
  for (int dh = 0; dh < 2; ++dh) {
#pragma unroll
    for (int a = 0; a < 4; ++a) {
      const f32x16 O = dh ? O1 : O0;
      bf16x4 t4;
#pragma unroll
      for (int c = 0; c < 4; ++c) t4[c] = (__bf16)(O[4 * a + c] * inv);
      *(bf16x4*)(Tw + ln * 72 + dh * 32 + 8 * a + 4 * g) = t4;
    }
  }
  const int q0 = qb * 128 + wave * 32;
#pragma unroll
  for (int i = 0; i < 4; ++i) {
    const int rq = i * 8 + (lane >> 3);
    const int c8 = (lane & 7) * 8;
    bf16x8 o = *(const bf16x8*)(Tw + rq * 72 + c8);
    size_t base = (((size_t)bz * Sn + q0 + rq) * Hn + h) * Dn + c8;
    *(bf16x8*)&Cc[base] = o;
  }
}

// ---------------------------------------------------------------- projection
// out(4096,1024) = concat @ W + b. 128x64 tile, 512 threads = 8 waves
// (wave = M-quadrant mq x N-half nh), dbuf, one barrier/iter. 16 waves/CU.
__global__ __launch_bounds__(512, 2) void proj(
    const __bf16* __restrict__ A, const __bf16* __restrict__ Wt,
    const float* __restrict__ bias, float* __restrict__ out) {
  const int tid = threadIdx.x, wave = tid >> 6, lane = tid & 63;
  const int ln = lane & 31, g = lane >> 5;
  const int mq = wave >> 1, nh = wave & 1;
  const int bm = blockIdx.x, bn = blockIdx.y;
  __shared__ __bf16 As[2][128][72];
  __shared__ __bf16 Bs[2][64][72];
  const int ar = tid >> 2, ac = (tid & 3) * 16;   // A: 2 b128/thread
  const int rb = tid >> 3, cb = (tid & 7) * 8;    // B: 1 b128/thread
  f32x16 acc = {};
  const __bf16* Ap = A + (size_t)(bm * 128) * DM;
  const __bf16* Wp = Wt + (size_t)(bn * 64) * DM;

  bf16x8 a0, a1, b0;
  {
    const __bf16* ap = Ap + (size_t)ar * DM + ac;
    a0 = *(const bf16x8*)ap; a1 = *(const bf16x8*)(ap + 8);
    b0 = *(const bf16x8*)(Wp + (size_t)rb * DM + cb);
  }
  *(bf16x8*)&As[0][ar][ac]     = a0;
  *(bf16x8*)&As[0][ar][ac + 8] = a1;
  *(bf16x8*)&Bs[0][rb][cb]     = b0;
  {
    const __bf16* ap = Ap + (size_t)ar * DM + 64 + ac;
    a0 = *(const bf16x8*)ap; a1 = *(const bf16x8*)(ap + 8);
    b0 = *(const bf16x8*)(Wp + (size_t)rb * DM + 64 + cb);
  }
  __syncthreads();

  constexpr int KT = DM / 64;
  for (int kt = 0; kt < KT; ++kt) {
    const int buf = kt & 1;
#pragma unroll
    for (int ks = 0; ks < 4; ++ks) {
      bf16x8 af = *(const bf16x8*)&As[buf][mq * 32 + ln][ks * 16 + g * 8];
      bf16x8 wf = *(const bf16x8*)&Bs[buf][nh * 32 + ln][ks * 16 + g * 8];
      acc = __builtin_amdgcn_mfma_f32_32x32x16_bf16(af, wf, acc, 0, 0, 0);
    }
    if (kt + 1 < KT) {
      const int nb = buf ^ 1;
      *(bf16x8*)&As[nb][ar][ac]     = a0;
      *(bf16x8*)&As[nb][ar][ac + 8] = a1;
      *(bf16x8*)&Bs[nb][rb][cb]     = b0;
      if (kt + 2 < KT) {
        const __bf16* ap = Ap + (size_t)ar * DM + (kt + 2) * 64 + ac;
        a0 = *(const bf16x8*)ap; a1 = *(const bf16x8*)(ap + 8);
        b0 = *(const bf16x8*)(Wp + (size_t)rb * DM + (kt + 2) * 64 + cb);
      }
    }
    __syncthreads();
  }
  const float bv = bias[bn * 64 + nh * 32 + ln];
#pragma unroll
  for (int r = 0; r < 16; ++r) {
    int row = bm * 128 + mq * 32 + (r & 3) + 8 * (r >> 2) + 4 * g;
    out[(size_t)row * DM + bn * 64 + nh * 32 + ln] = acc[r] + bv;
  }
}

// ---------------------------------------------------------------- launch
extern "C" void kernel_launch(void* const* d_in, const int* in_sizes, int n_in,
                              void* d_out, int out_size, void* d_ws, size_t ws_size,
                              hipStream_t stream) {
  const float* Q = (const float*)d_in[0];
  const float* K = (const float*)d_in[1];
  const float* V = (const float*)d_in[2];
  const float* W = (const float*)d_in[3];
  const float* b = (const float*)d_in[4];
  float* out = (float*)d_out;

  __bf16* ws  = (__bf16*)d_ws;
  __bf16* Kf  = ws;                           // K fragment stream
  __bf16* Vf  = Kf + QKV_ELEMS;               // V fragment stream
  __bf16* Cc  = Vf + QKV_ELEMS;               // concat (B,S,H,D) bf16
  __bf16* Wt  = Cc + QKV_ELEMS;               // (n,k) bf16

  convert_all<<<dim3(1536, 1, 1), 256, 0, stream>>>(K, V, W, Kf, Vf, Wt);
  attn<<<dim3(Sn / 128, Hn, Bn), 256, 0, stream>>>(Q, Kf, Vf, Cc);
  proj<<<dim3(Bn * Sn / 128, DM / 64, 1), 512, 0, stream>>>(Cc, Wt, b, out);
}